// Round 5
// baseline (299.346 us; speedup 1.0000x reference)
//
#include <hip/hip_runtime.h>
#include <hip/hip_bf16.h>

// Problem constants
#define B_   2
#define N_   2048
#define D_   128
#define H_   16
#define ALL_ 2048
#define M_   (B_*N_)    // 4096 total rows
#define BH_  (B_*H_)    // 32 (batch*heads)

typedef __bf16 bf16;
typedef __bf16 bf16x8 __attribute__((ext_vector_type(8)));
typedef __bf16 bf16x4 __attribute__((ext_vector_type(4)));
typedef float  floatx4 __attribute__((ext_vector_type(4)));

#define MFMA32K(a,b,c) __builtin_amdgcn_mfma_f32_16x16x32_bf16((a),(b),(c),0,0,0)

// async global->LDS DMA, 16B per lane (m97 pattern)
__device__ inline void load_lds16(const bf16* g, bf16* l) {
    __builtin_amdgcn_global_load_lds((const __attribute__((address_space(1))) void*)g,
                                     (__attribute__((address_space(3))) void*)l, 16, 0, 0);
}

// ---------------------------------------------------------------------------
// Kernel T: weight prep via LDS tiled transpose (32x32 tiles); mask -> bias.
// ---------------------------------------------------------------------------
__global__ __launch_bounds__(256) void prep_weights(const float* __restrict__ Wq,
                                                    const float* __restrict__ Wk,
                                                    const float* __restrict__ Wv,
                                                    const float* __restrict__ Wo,
                                                    const int* __restrict__ mask,
                                                    bf16* __restrict__ Wqt,
                                                    bf16* __restrict__ Wkt,
                                                    bf16* __restrict__ Wvt,
                                                    bf16* __restrict__ Wot,
                                                    float* __restrict__ mbias) {
    int bid = blockIdx.x, tid = threadIdx.x;
    if (bid >= 1024) {
        int e = (bid - 1024) * 256 + tid;
        mbias[e] = mask[e] ? 0.0f : -30.0f;
        return;
    }
    __shared__ float tile[32][33];
    const float* W; bf16* Wt; int R, C, tr, tc;
    if (bid < 768) {
        int m = bid >> 8;
        W  = (m == 0) ? Wq  : (m == 1) ? Wk  : Wv;
        Wt = (m == 0) ? Wqt : (m == 1) ? Wkt : Wvt;
        R = 128; C = 2048;
        int t = bid & 255; tr = t >> 6; tc = t & 63;
    } else {
        W = Wo; Wt = Wot; R = 2048; C = 128;
        int t = bid - 768; tr = t >> 2; tc = t & 3;
    }
    int rr = tid >> 5, cc = tid & 31;
#pragma unroll
    for (int i = 0; i < 4; i++)
        tile[rr + i * 8][cc] = W[(size_t)(tr * 32 + rr + i * 8) * C + tc * 32 + cc];
    __syncthreads();
#pragma unroll
    for (int i = 0; i < 4; i++)
        Wt[(size_t)(tc * 32 + rr + i * 8) * R + tr * 32 + cc] = (bf16)tile[cc][rr + i * 8];
}

// ---------------------------------------------------------------------------
// Kernel A: fused Q+K+V projection in ONE block: A-frags (x rows) loaded once,
// reused for all three weight matrices (x L2 traffic /3, grid 6144 -> 2048).
// Output layouts (exactly what flash_attn stages):
//   Q row-major [bh][n][128]
//   K FRAGMENT-MAJOR: Kf[bh][kb][s][kf][lane][8]
//   V FRAGMENT-MAJOR: Vf[bh][kb][nf][g][lane][8]
// ---------------------------------------------------------------------------
__global__ __launch_bounds__(256) void qkv_proj(const float* __restrict__ x,
                                                const float* __restrict__ bq,
                                                const float* __restrict__ bk,
                                                const float* __restrict__ bv,
                                                const bf16* __restrict__ Wqt,
                                                const bf16* __restrict__ Wkt,
                                                const bf16* __restrict__ Wvt,
                                                bf16* __restrict__ Qb,
                                                bf16* __restrict__ Kf,
                                                bf16* __restrict__ Vf) {
    __shared__ bf16 tile[64][76];

    int tid = threadIdx.x;
    int wave = tid >> 6, lane = tid & 63;
    int lrow = lane & 15, quad = lane >> 4;
    int r0b = blockIdx.x * 64;
    int r0 = r0b + wave * 16;                 // global row (b*N + n)
    int c0 = blockIdx.y * 64;                 // global col (h*128 + dim)

    bf16x8 a[4];
    const float* xr = x + (size_t)(r0 + lrow) * 128 + quad * 8;
#pragma unroll
    for (int kf = 0; kf < 4; kf++) {
        const float* p = xr + kf * 32;
        float4 u0 = *(const float4*)p;
        float4 u1 = *(const float4*)(p + 4);
        bf16x8 t;
        t[0]=(bf16)u0.x; t[1]=(bf16)u0.y; t[2]=(bf16)u0.z; t[3]=(bf16)u0.w;
        t[4]=(bf16)u1.x; t[5]=(bf16)u1.y; t[6]=(bf16)u1.z; t[7]=(bf16)u1.w;
        a[kf] = t;
    }

    int bb = r0b >> 11;            // batch
    int h  = c0 >> 7;              // head
    int bhw = bb * 16 + h;
    int kbt = (r0b & 2047) >> 6;   // 64-key tile index
    floatx4 zero4 = {0.f, 0.f, 0.f, 0.f};

    for (int z = 0; z < 3; z++) {
        const float* bias = (z == 0) ? bq : (z == 1) ? bk : bv;
        const bf16*  Wt   = (z == 0) ? Wqt : (z == 1) ? Wkt : Wvt;

        floatx4 acc[4] = {zero4, zero4, zero4, zero4};
#pragma unroll
        for (int kf = 0; kf < 4; kf++) {
#pragma unroll
            for (int nf = 0; nf < 4; nf++) {
                bf16x8 b = *(const bf16x8*)(Wt + (size_t)(c0 + nf * 16 + lrow) * 128 + kf * 32 + quad * 8);
                acc[nf] = MFMA32K(a[kf], b, acc[nf]);
            }
        }

        // stage (+bias, cast). z<2: [row][col]; z==2: [col][row]
#pragma unroll
        for (int nf = 0; nf < 4; nf++) {
            int col = nf * 16 + lrow;
            float bvv = bias[c0 + col];
#pragma unroll
            for (int r = 0; r < 4; r++) {
                int row = wave * 16 + quad * 4 + r;
                bf16 val = (bf16)(acc[nf][r] + bvv);
                if (z < 2) tile[row][col] = val;
                else       tile[col][row] = val;
            }
        }
        __syncthreads();

        if (z == 0) {
            int row = tid >> 2, ch = (tid & 3) * 16;
            bf16x8 w0 = *(const bf16x8*)(&tile[row][ch]);
            bf16x8 w1 = *(const bf16x8*)(&tile[row][ch + 8]);
            int n = (r0b + row) & 2047;
            int dim = (c0 & 127) + ch;
            bf16* dst = Qb + (((size_t)bhw * N_ + n) << 7) + dim;
            *(bf16x8*)dst = w0;
            *(bf16x8*)(dst + 8) = w1;
        } else if (z == 1) {
            int s = tid >> 6, lr = lane & 15, qd = lane >> 4;
            int kfbase = (c0 & 127) >> 5;          // 0 or 2
            size_t fbase = ((size_t)bhw * 32 + kbt) * 16 + (size_t)(s * 4 + kfbase);
#pragma unroll
            for (int kfl = 0; kfl < 2; kfl++) {
                bf16x8 w = *(const bf16x8*)(&tile[s * 16 + lr][kfl * 32 + qd * 8]);
                *(bf16x8*)(Kf + (fbase + kfl) * 512 + lane * 8) = w;
            }
        } else {
            int nfl = tid >> 6, lr = lane & 15, qd = lane >> 4;
            int nfbase = (c0 & 127) >> 4;          // 0 or 4
            size_t fbase = (((size_t)bhw * 32 + kbt) * 8 + (nfbase + nfl)) * 2;
#pragma unroll
            for (int g = 0; g < 2; g++) {
                bf16x4 a0 = *(const bf16x4*)(&tile[nfl * 16 + lr][g * 32 + qd * 4]);
                bf16x4 a1 = *(const bf16x4*)(&tile[nfl * 16 + lr][g * 32 + 16 + qd * 4]);
                bf16x8 w;
                w[0]=a0[0]; w[1]=a0[1]; w[2]=a0[2]; w[3]=a0[3];
                w[4]=a1[0]; w[5]=a1[1]; w[6]=a1[2]; w[7]=a1[3];
                *(bf16x8*)(Vf + (fbase + g) * 512 + lane * 8) = w;
            }
        }
        __syncthreads();   // tile reused by next z
    }
}

// ---------------------------------------------------------------------------
// Kernel B: flash attention. 2 waves/block, 64 q/WAVE (u=4), 128 q/block.
// MFMA per wave-iter doubles to 128 while ds_reads stay 32 (K/V frags shared
// across all 4 q-tiles); staging traffic & barrier count halve vs R4.
// PV for a 32-key group runs right after its two S-tiles (small live pf).
// launch_bounds(128,2) caps VGPR at 256 (2 waves/SIMD).
// ---------------------------------------------------------------------------
__global__ __launch_bounds__(128, 2) void flash_attn(const bf16* __restrict__ Q,
                                                     const bf16* __restrict__ Kf,
                                                     const bf16* __restrict__ Vf,
                                                     const float* __restrict__ mbias,
                                                     const int* __restrict__ mask,
                                                     bf16* __restrict__ ctx) {
    __shared__ bf16 sm[16384];   // [0,8192): K frags, [8192,16384): V frags

    int tid = threadIdx.x;
    int wave = tid >> 6, lane = tid & 63;
    int lrow = lane & 15, quad = lane >> 4;
    int bh = blockIdx.y;
    int b  = bh >> 4;
    int q0 = blockIdx.x * 128 + wave * 64;

    const bf16* Qp = Q + (size_t)bh * N_ * 128;
    const float* mbp = mbias + b * N_;

    // Q B-frags (B[k=d=quad*8+j][n=q=lane&15]) for 4 q-tiles, held all loop
    bf16x8 qf[4][4];
#pragma unroll
    for (int u = 0; u < 4; u++)
#pragma unroll
        for (int kf = 0; kf < 4; kf++)
            qf[u][kf] = *(const bf16x8*)(Qp + (size_t)(q0 + u * 16 + lrow) * 128 + kf * 32 + quad * 8);

    floatx4 zero4 = {0.f, 0.f, 0.f, 0.f};
    floatx4 O[4][8];
#pragma unroll
    for (int u = 0; u < 4; u++)
#pragma unroll
        for (int nf = 0; nf < 8; nf++) O[u][nf] = zero4;
    float lp[4] = {0.f, 0.f, 0.f, 0.f};

    const float scale = 0.0883883476483184f;   // 1/sqrt(128)

    for (int kb = 0; kb < 32; kb++) {
        const bf16* ksrc = Kf + ((size_t)bh * 32 + kb) * 8192;
        const bf16* vsrc = Vf + ((size_t)bh * 32 + kb) * 8192;
        // ---- stage 32KB via async DMA: 16 segs K + 16 segs V, split by wave ----
#pragma unroll
        for (int i = 0; i < 8; i++) {
            int seg = wave * 8 + i;            // 0..15, 512 elems (1KB) each
            load_lds16(ksrc + seg * 512 + lane * 8, &sm[seg * 512]);
            load_lds16(vsrc + seg * 512 + lane * 8, &sm[8192 + seg * 512]);
        }
        __syncthreads();

        // ---- per 32-key group: two S-tiles -> exp -> PV (full-rate K=32) ----
#pragma unroll
        for (int sp = 0; sp < 2; sp++) {
            bf16x8 pf[4];
#pragma unroll
            for (int si = 0; si < 2; si++) {
                int s = sp * 2 + si;
                floatx4 S[4] = {zero4, zero4, zero4, zero4};
#pragma unroll
                for (int kf = 0; kf < 4; kf++) {
                    bf16x8 kfr = *(const bf16x8*)(&sm[((s * 4 + kf) * 64 + lane) * 8]);
#pragma unroll
                    for (int u = 0; u < 4; u++) S[u] = MFMA32K(kfr, qf[u][kf], S[u]);
                }
                float4 mb4 = *(const float4*)(mbp + kb * 64 + s * 16 + quad * 4);
                const float* mbr = (const float*)&mb4;
#pragma unroll
                for (int u = 0; u < 4; u++)
#pragma unroll
                    for (int r = 0; r < 4; r++) {
                        float p = __expf(fmaf(S[u][r], scale, mbr[r]));
                        lp[u] += p;
                        pf[u][si * 4 + r] = (bf16)p;
                    }
            }
#pragma unroll
            for (int nf = 0; nf < 8; nf++) {
                bf16x8 vfr = *(const bf16x8*)(&sm[8192 + ((nf * 2 + sp) * 64 + lane) * 8]);
#pragma unroll
                for (int u = 0; u < 4; u++) O[u][nf] = MFMA32K(vfr, pf[u], O[u][nf]);
            }
        }
        __syncthreads();   // all reads done before next iter's DMA overwrites
    }

    // ---- epilogue: reduce l across quads, normalize, query-mask, store ----
    const int* mp = mask + b * N_;
#pragma unroll
    for (int u = 0; u < 4; u++) {
        float lsum = lp[u];
        lsum += __shfl_xor(lsum, 16, 64);
        lsum += __shfl_xor(lsum, 32, 64);
        int q = q0 + u * 16 + lrow;
        int qm = mp[q];
        float rl = (qm && lsum > 0.f) ? (1.0f / lsum) : 0.f;
        bf16* cp = ctx + ((size_t)b * N_ + q) * ALL_ + (bh & 15) * 128 + quad * 4;
#pragma unroll
        for (int nf = 0; nf < 8; nf++) {
            bf16x4 o;
#pragma unroll
            for (int j = 0; j < 4; j++) o[j] = (bf16)(O[u][nf][j] * rl);
            *(bf16x4*)(cp + nf * 16) = o;   // d = nf*16 + quad*4 + j
        }
    }
}

// ---------------------------------------------------------------------------
// Kernel C: out = ctx(4096x2048) @ Wo(2048x128) + bo, fp32 out.
// ---------------------------------------------------------------------------
__global__ __launch_bounds__(64) void out_proj(const bf16* __restrict__ ctx,
                                               const bf16* __restrict__ Wot,
                                               const float* __restrict__ bo,
                                               float* __restrict__ out) {
    int lane = threadIdx.x;
    int lrow = lane & 15, quad = lane >> 4;
    int r0 = blockIdx.x * 16;
    int c0 = blockIdx.y * 32;

    floatx4 zero4 = {0.f, 0.f, 0.f, 0.f};
    floatx4 acc[2] = {zero4, zero4};
    const bf16* cr = ctx + (size_t)(r0 + lrow) * ALL_ + quad * 8;
    const bf16* w0 = Wot + (size_t)(c0 + lrow) * ALL_ + quad * 8;
    const bf16* w1 = w0 + 16 * ALL_;
#pragma unroll 4
    for (int k0 = 0; k0 < ALL_; k0 += 32) {
        bf16x8 a  = *(const bf16x8*)(cr + k0);
        bf16x8 b0 = *(const bf16x8*)(w0 + k0);
        bf16x8 b1 = *(const bf16x8*)(w1 + k0);
        acc[0] = MFMA32K(a, b0, acc[0]);
        acc[1] = MFMA32K(a, b1, acc[1]);
    }
#pragma unroll
    for (int nf = 0; nf < 2; nf++) {
        int col = c0 + nf * 16 + lrow;
        float bv = bo[col];
#pragma unroll
        for (int r = 0; r < 4; r++) {
            int m = r0 + quad * 4 + r;
            out[(size_t)m * 128 + col] = acc[nf][r] + bv;
        }
    }
}

// ---------------------------------------------------------------------------
extern "C" void kernel_launch(void* const* d_in, const int* in_sizes, int n_in,
                              void* d_out, int out_size, void* d_ws, size_t ws_size,
                              hipStream_t stream) {
    const float* x    = (const float*)d_in[0];
    const int*   mask = (const int*)d_in[1];
    const float* Wq   = (const float*)d_in[2];
    const float* bq   = (const float*)d_in[3];
    const float* Wk   = (const float*)d_in[4];
    const float* bk   = (const float*)d_in[5];
    const float* Wv   = (const float*)d_in[6];
    const float* bv   = (const float*)d_in[7];
    const float* Wo   = (const float*)d_in[8];
    const float* bo   = (const float*)d_in[9];
    float* out = (float*)d_out;

    char* ws = (char*)d_ws;
    size_t off = 0;
    bf16* Wqt = (bf16*)(ws + off); off += (size_t)2048 * 128 * 2;
    bf16* Wkt = (bf16*)(ws + off); off += (size_t)2048 * 128 * 2;
    bf16* Wvt = (bf16*)(ws + off); off += (size_t)2048 * 128 * 2;
    bf16* Wot = (bf16*)(ws + off); off += (size_t)128 * 2048 * 2;
    size_t qkv_elems = (size_t)BH_ * N_ * 128;           // 8.4M
    bf16* Qb  = (bf16*)(ws + off); off += qkv_elems * 2; // 16 MB
    bf16* Kf  = (bf16*)(ws + off); off += qkv_elems * 2; // fragment-major
    bf16* Vf  = (bf16*)(ws + off); off += qkv_elems * 2; // fragment-major
    bf16* ctx = (bf16*)(ws + off); off += (size_t)M_ * ALL_ * 2;
    float* mbias = (float*)(ws + off); off += (size_t)B_ * N_ * 4;
    (void)ws_size; (void)in_sizes; (void)n_in; (void)out_size;

    prep_weights<<<1040, 256, 0, stream>>>(Wq, Wk, Wv, Wo, mask,
                                           Wqt, Wkt, Wvt, Wot, mbias);

    qkv_proj<<<dim3(64, 32), 256, 0, stream>>>(x, bq, bk, bv, Wqt, Wkt, Wvt,
                                               Qb, Kf, Vf);

    flash_attn<<<dim3(16, 32), 128, 0, stream>>>(Qb, Kf, Vf, mbias, mask, ctx);

    out_proj<<<dim3(256, 4), 64, 0, stream>>>(ctx, Wot, bo, out);
}

// Round 6
// 242.171 us; speedup vs baseline: 1.2361x; 1.2361x over previous
//
#include <hip/hip_runtime.h>
#include <hip/hip_bf16.h>

// Problem constants
#define B_   2
#define N_   2048
#define D_   128
#define H_   16
#define ALL_ 2048
#define M_   (B_*N_)    // 4096 total rows
#define BH_  (B_*H_)    // 32 (batch*heads)

typedef __bf16 bf16;
typedef __bf16 bf16x8 __attribute__((ext_vector_type(8)));
typedef __bf16 bf16x4 __attribute__((ext_vector_type(4)));
typedef float  floatx4 __attribute__((ext_vector_type(4)));

#define MFMA32K(a,b,c) __builtin_amdgcn_mfma_f32_16x16x32_bf16((a),(b),(c),0,0,0)

// async global->LDS DMA, 16B per lane (m97 pattern)
__device__ inline void load_lds16(const bf16* g, bf16* l) {
    __builtin_amdgcn_global_load_lds((const __attribute__((address_space(1))) void*)g,
                                     (__attribute__((address_space(3))) void*)l, 16, 0, 0);
}

// ---------------------------------------------------------------------------
// Kernel T: weight prep via LDS tiled transpose (32x32 tiles); mask -> bias.
// ---------------------------------------------------------------------------
__global__ __launch_bounds__(256) void prep_weights(const float* __restrict__ Wq,
                                                    const float* __restrict__ Wk,
                                                    const float* __restrict__ Wv,
                                                    const float* __restrict__ Wo,
                                                    const int* __restrict__ mask,
                                                    bf16* __restrict__ Wqt,
                                                    bf16* __restrict__ Wkt,
                                                    bf16* __restrict__ Wvt,
                                                    bf16* __restrict__ Wot,
                                                    float* __restrict__ mbias) {
    int bid = blockIdx.x, tid = threadIdx.x;
    if (bid >= 1024) {
        int e = (bid - 1024) * 256 + tid;
        mbias[e] = mask[e] ? 0.0f : -30.0f;
        return;
    }
    __shared__ float tile[32][33];
    const float* W; bf16* Wt; int R, C, tr, tc;
    if (bid < 768) {
        int m = bid >> 8;
        W  = (m == 0) ? Wq  : (m == 1) ? Wk  : Wv;
        Wt = (m == 0) ? Wqt : (m == 1) ? Wkt : Wvt;
        R = 128; C = 2048;
        int t = bid & 255; tr = t >> 6; tc = t & 63;
    } else {
        W = Wo; Wt = Wot; R = 2048; C = 128;
        int t = bid - 768; tr = t >> 2; tc = t & 3;
    }
    int rr = tid >> 5, cc = tid & 31;
#pragma unroll
    for (int i = 0; i < 4; i++)
        tile[rr + i * 8][cc] = W[(size_t)(tr * 32 + rr + i * 8) * C + tc * 32 + cc];
    __syncthreads();
#pragma unroll
    for (int i = 0; i < 4; i++)
        Wt[(size_t)(tc * 32 + rr + i * 8) * R + tr * 32 + cc] = (bf16)tile[cc][rr + i * 8];
}

// ---------------------------------------------------------------------------
// Kernel A: fused Q+K+V projection in ONE block: A-frags (x rows) loaded once,
// reused for all three weight matrices. Output layouts (exactly what
// flash_attn stages):
//   Q row-major [bh][n][128]
//   K FRAGMENT-MAJOR: Kf[bh][kb][s][kf][lane][8]
//   V FRAGMENT-MAJOR: Vf[bh][kb][nf][g][lane][8]
// ---------------------------------------------------------------------------
__global__ __launch_bounds__(256) void qkv_proj(const float* __restrict__ x,
                                                const float* __restrict__ bq,
                                                const float* __restrict__ bk,
                                                const float* __restrict__ bv,
                                                const bf16* __restrict__ Wqt,
                                                const bf16* __restrict__ Wkt,
                                                const bf16* __restrict__ Wvt,
                                                bf16* __restrict__ Qb,
                                                bf16* __restrict__ Kf,
                                                bf16* __restrict__ Vf) {
    __shared__ bf16 tile[64][76];

    int tid = threadIdx.x;
    int wave = tid >> 6, lane = tid & 63;
    int lrow = lane & 15, quad = lane >> 4;
    int r0b = blockIdx.x * 64;
    int r0 = r0b + wave * 16;                 // global row (b*N + n)
    int c0 = blockIdx.y * 64;                 // global col (h*128 + dim)

    bf16x8 a[4];
    const float* xr = x + (size_t)(r0 + lrow) * 128 + quad * 8;
#pragma unroll
    for (int kf = 0; kf < 4; kf++) {
        const float* p = xr + kf * 32;
        float4 u0 = *(const float4*)p;
        float4 u1 = *(const float4*)(p + 4);
        bf16x8 t;
        t[0]=(bf16)u0.x; t[1]=(bf16)u0.y; t[2]=(bf16)u0.z; t[3]=(bf16)u0.w;
        t[4]=(bf16)u1.x; t[5]=(bf16)u1.y; t[6]=(bf16)u1.z; t[7]=(bf16)u1.w;
        a[kf] = t;
    }

    int bb = r0b >> 11;            // batch
    int h  = c0 >> 7;              // head
    int bhw = bb * 16 + h;
    int kbt = (r0b & 2047) >> 6;   // 64-key tile index
    floatx4 zero4 = {0.f, 0.f, 0.f, 0.f};

    for (int z = 0; z < 3; z++) {
        const float* bias = (z == 0) ? bq : (z == 1) ? bk : bv;
        const bf16*  Wt   = (z == 0) ? Wqt : (z == 1) ? Wkt : Wvt;

        floatx4 acc[4] = {zero4, zero4, zero4, zero4};
#pragma unroll
        for (int kf = 0; kf < 4; kf++) {
#pragma unroll
            for (int nf = 0; nf < 4; nf++) {
                bf16x8 b = *(const bf16x8*)(Wt + (size_t)(c0 + nf * 16 + lrow) * 128 + kf * 32 + quad * 8);
                acc[nf] = MFMA32K(a[kf], b, acc[nf]);
            }
        }

        // stage (+bias, cast). z<2: [row][col]; z==2: [col][row]
#pragma unroll
        for (int nf = 0; nf < 4; nf++) {
            int col = nf * 16 + lrow;
            float bvv = bias[c0 + col];
#pragma unroll
            for (int r = 0; r < 4; r++) {
                int row = wave * 16 + quad * 4 + r;
                bf16 val = (bf16)(acc[nf][r] + bvv);
                if (z < 2) tile[row][col] = val;
                else       tile[col][row] = val;
            }
        }
        __syncthreads();

        if (z == 0) {
            int row = tid >> 2, ch = (tid & 3) * 16;
            bf16x8 w0 = *(const bf16x8*)(&tile[row][ch]);
            bf16x8 w1 = *(const bf16x8*)(&tile[row][ch + 8]);
            int n = (r0b + row) & 2047;
            int dim = (c0 & 127) + ch;
            bf16* dst = Qb + (((size_t)bhw * N_ + n) << 7) + dim;
            *(bf16x8*)dst = w0;
            *(bf16x8*)(dst + 8) = w1;
        } else if (z == 1) {
            int s = tid >> 6, lr = lane & 15, qd = lane >> 4;
            int kfbase = (c0 & 127) >> 5;          // 0 or 2
            size_t fbase = ((size_t)bhw * 32 + kbt) * 16 + (size_t)(s * 4 + kfbase);
#pragma unroll
            for (int kfl = 0; kfl < 2; kfl++) {
                bf16x8 w = *(const bf16x8*)(&tile[s * 16 + lr][kfl * 32 + qd * 8]);
                *(bf16x8*)(Kf + (fbase + kfl) * 512 + lane * 8) = w;
            }
        } else {
            int nfl = tid >> 6, lr = lane & 15, qd = lane >> 4;
            int nfbase = (c0 & 127) >> 4;          // 0 or 4
            size_t fbase = (((size_t)bhw * 32 + kbt) * 8 + (nfbase + nfl)) * 2;
#pragma unroll
            for (int g = 0; g < 2; g++) {
                bf16x4 a0 = *(const bf16x4*)(&tile[nfl * 16 + lr][g * 32 + qd * 4]);
                bf16x4 a1 = *(const bf16x4*)(&tile[nfl * 16 + lr][g * 32 + 16 + qd * 4]);
                bf16x8 w;
                w[0]=a0[0]; w[1]=a0[1]; w[2]=a0[2]; w[3]=a0[3];
                w[4]=a1[0]; w[5]=a1[1]; w[6]=a1[2]; w[7]=a1[3];
                *(bf16x8*)(Vf + (fbase + g) * 512 + lane * 8) = w;
            }
        }
        __syncthreads();   // tile reused by next z
    }
}

// ---------------------------------------------------------------------------
// Kernel B: flash attention. 4 waves/block (256 thr), u=2 per wave (32 q),
// 128 q/block -> K/V L2 re-reads halve vs R4 (16 q-blocks per bh, was 32).
// No launch_bounds reg cap (R5's spill lesson: u=2 fits ~90 VGPR naturally).
// XCD swizzle: all 16 q-blocks of one bh share bid&7 -> same XCD's L2 keeps
// that bh's 2MB K/V frag set hot. Staging = identity DMA, conflict-free
// ds_read_b128, S^T trick, full-rate K=32 PV (all verified R2-R4).
// ---------------------------------------------------------------------------
__global__ __launch_bounds__(256) void flash_attn(const bf16* __restrict__ Q,
                                                  const bf16* __restrict__ Kf,
                                                  const bf16* __restrict__ Vf,
                                                  const float* __restrict__ mbias,
                                                  const int* __restrict__ mask,
                                                  bf16* __restrict__ ctx) {
    __shared__ bf16 sm[16384];   // [0,8192): K frags, [8192,16384): V frags

    int tid = threadIdx.x;
    int wave = tid >> 6, lane = tid & 63;
    int lrow = lane & 15, quad = lane >> 4;
    // XCD swizzle: 512 blocks = 8 xcd * (4 bh * 16 qblk)
    int bid = blockIdx.x;
    int xcd = bid & 7, seq = bid >> 3;          // seq 0..63
    int bh  = xcd * 4 + (seq >> 4);             // 0..31
    int qblk = seq & 15;                        // 0..15
    int b  = bh >> 4;
    int q0 = qblk * 128 + wave * 32;

    const bf16* Qp = Q + (size_t)bh * N_ * 128;
    const float* mbp = mbias + b * N_;

    // Q B-frags (B[k=d=quad*8+j][n=q=lane&15]) for 2 q-tiles, held all loop
    bf16x8 qf[2][4];
#pragma unroll
    for (int u = 0; u < 2; u++)
#pragma unroll
        for (int kf = 0; kf < 4; kf++)
            qf[u][kf] = *(const bf16x8*)(Qp + (size_t)(q0 + u * 16 + lrow) * 128 + kf * 32 + quad * 8);

    floatx4 zero4 = {0.f, 0.f, 0.f, 0.f};
    floatx4 O[2][8];
#pragma unroll
    for (int u = 0; u < 2; u++)
#pragma unroll
        for (int nf = 0; nf < 8; nf++) O[u][nf] = zero4;
    float lp[2] = {0.f, 0.f};

    const float scale = 0.0883883476483184f;   // 1/sqrt(128)

    for (int kb = 0; kb < 32; kb++) {
        const bf16* ksrc = Kf + ((size_t)bh * 32 + kb) * 8192;
        const bf16* vsrc = Vf + ((size_t)bh * 32 + kb) * 8192;
        // ---- stage 32KB via async DMA: 32 segs of 1KB split over 4 waves ----
#pragma unroll
        for (int i = 0; i < 4; i++) {
            int seg = wave * 4 + i;            // 0..15
            load_lds16(ksrc + seg * 512 + lane * 8, &sm[seg * 512]);
            load_lds16(vsrc + seg * 512 + lane * 8, &sm[8192 + seg * 512]);
        }
        __syncthreads();

        // ---- S^T per 16-key tile; exp; pack into K=32 B-frags ----
        bf16x8 pf[2][2];
#pragma unroll
        for (int s = 0; s < 4; s++) {
            floatx4 S0 = zero4, S1 = zero4;
#pragma unroll
            for (int kf = 0; kf < 4; kf++) {
                bf16x8 kfr = *(const bf16x8*)(&sm[((s * 4 + kf) * 64 + lane) * 8]);
                S0 = MFMA32K(kfr, qf[0][kf], S0);
                S1 = MFMA32K(kfr, qf[1][kf], S1);
            }
            float4 mb4 = *(const float4*)(mbp + kb * 64 + s * 16 + quad * 4);
            const float* mbr = (const float*)&mb4;
            int g = s >> 1, o = (s & 1) * 4;
#pragma unroll
            for (int r = 0; r < 4; r++) {
                float p0 = __expf(fmaf(S0[r], scale, mbr[r]));
                float p1 = __expf(fmaf(S1[r], scale, mbr[r]));
                lp[0] += p0; lp[1] += p1;
                pf[0][g][o + r] = (bf16)p0;
                pf[1][g][o + r] = (bf16)p1;
            }
        }

        // ---- PV: O^T[d][q] += V^T P, full-rate K=32 ----
#pragma unroll
        for (int nf = 0; nf < 8; nf++) {
#pragma unroll
            for (int g = 0; g < 2; g++) {
                bf16x8 vfr = *(const bf16x8*)(&sm[8192 + ((nf * 2 + g) * 64 + lane) * 8]);
                O[0][nf] = MFMA32K(vfr, pf[0][g], O[0][nf]);
                O[1][nf] = MFMA32K(vfr, pf[1][g], O[1][nf]);
            }
        }
        __syncthreads();   // all reads done before next iter's DMA overwrites
    }

    // ---- epilogue: reduce l across quads, normalize, query-mask, store ----
    const int* mp = mask + b * N_;
#pragma unroll
    for (int u = 0; u < 2; u++) {
        float lsum = lp[u];
        lsum += __shfl_xor(lsum, 16, 64);
        lsum += __shfl_xor(lsum, 32, 64);
        int q = q0 + u * 16 + lrow;
        int qm = mp[q];
        float rl = (qm && lsum > 0.f) ? (1.0f / lsum) : 0.f;
        bf16* cp = ctx + ((size_t)b * N_ + q) * ALL_ + (bh & 15) * 128 + quad * 4;
#pragma unroll
        for (int nf = 0; nf < 8; nf++) {
            bf16x4 o;
#pragma unroll
            for (int j = 0; j < 4; j++) o[j] = (bf16)(O[u][nf][j] * rl);
            *(bf16x4*)(cp + nf * 16) = o;   // d = nf*16 + quad*4 + j
        }
    }
}

// ---------------------------------------------------------------------------
// Kernel C: out = ctx(4096x2048) @ Wo(2048x128) + bo, fp32 out.
// One wave per block, 16 rows x 16 cols -> 2048 blocks (8 waves/CU for
// latency hiding; Wot re-reads are L2-resident).
// ---------------------------------------------------------------------------
__global__ __launch_bounds__(64) void out_proj(const bf16* __restrict__ ctx,
                                               const bf16* __restrict__ Wot,
                                               const float* __restrict__ bo,
                                               float* __restrict__ out) {
    int lane = threadIdx.x;
    int lrow = lane & 15, quad = lane >> 4;
    int r0 = blockIdx.x * 16;
    int c0 = blockIdx.y * 16;

    floatx4 zero4 = {0.f, 0.f, 0.f, 0.f};
    floatx4 acc = zero4;
    const bf16* cr = ctx + (size_t)(r0 + lrow) * ALL_ + quad * 8;
    const bf16* w0 = Wot + (size_t)(c0 + lrow) * ALL_ + quad * 8;
#pragma unroll 8
    for (int k0 = 0; k0 < ALL_; k0 += 32) {
        bf16x8 a  = *(const bf16x8*)(cr + k0);
        bf16x8 b0 = *(const bf16x8*)(w0 + k0);
        acc = MFMA32K(a, b0, acc);
    }
    int col = c0 + lrow;
    float bv = bo[col];
#pragma unroll
    for (int r = 0; r < 4; r++) {
        int m = r0 + quad * 4 + r;
        out[(size_t)m * 128 + col] = acc[r] + bv;
    }
}

// ---------------------------------------------------------------------------
extern "C" void kernel_launch(void* const* d_in, const int* in_sizes, int n_in,
                              void* d_out, int out_size, void* d_ws, size_t ws_size,
                              hipStream_t stream) {
    const float* x    = (const float*)d_in[0];
    const int*   mask = (const int*)d_in[1];
    const float* Wq   = (const float*)d_in[2];
    const float* bq   = (const float*)d_in[3];
    const float* Wk   = (const float*)d_in[4];
    const float* bk   = (const float*)d_in[5];
    const float* Wv   = (const float*)d_in[6];
    const float* bv   = (const float*)d_in[7];
    const float* Wo   = (const float*)d_in[8];
    const float* bo   = (const float*)d_in[9];
    float* out = (float*)d_out;

    char* ws = (char*)d_ws;
    size_t off = 0;
    bf16* Wqt = (bf16*)(ws + off); off += (size_t)2048 * 128 * 2;
    bf16* Wkt = (bf16*)(ws + off); off += (size_t)2048 * 128 * 2;
    bf16* Wvt = (bf16*)(ws + off); off += (size_t)2048 * 128 * 2;
    bf16* Wot = (bf16*)(ws + off); off += (size_t)128 * 2048 * 2;
    size_t qkv_elems = (size_t)BH_ * N_ * 128;           // 8.4M
    bf16* Qb  = (bf16*)(ws + off); off += qkv_elems * 2; // 16 MB
    bf16* Kf  = (bf16*)(ws + off); off += qkv_elems * 2; // fragment-major
    bf16* Vf  = (bf16*)(ws + off); off += qkv_elems * 2; // fragment-major
    bf16* ctx = (bf16*)(ws + off); off += (size_t)M_ * ALL_ * 2;
    float* mbias = (float*)(ws + off); off += (size_t)B_ * N_ * 4;
    (void)ws_size; (void)in_sizes; (void)n_in; (void)out_size;

    prep_weights<<<1040, 256, 0, stream>>>(Wq, Wk, Wv, Wo, mask,
                                           Wqt, Wkt, Wvt, Wot, mbias);

    qkv_proj<<<dim3(64, 32), 256, 0, stream>>>(x, bq, bk, bv, Wqt, Wkt, Wvt,
                                               Qb, Kf, Vf);

    flash_attn<<<512, 256, 0, stream>>>(Qb, Kf, Vf, mbias, mask, ctx);

    out_proj<<<dim3(256, 8), 64, 0, stream>>>(ctx, Wot, bo, out);
}